// Round 2
// baseline (365.856 us; speedup 1.0000x reference)
//
#include <hip/hip_runtime.h>
#include <math.h>

// Problem constants (from reference)
constexpr int B_SZ = 16384;
constexpr int G_SZ = 256;
constexpr long long CELLS = (long long)B_SZ * G_SZ;  // 4,194,304 cells; 2 anchor slots each
constexpr int CLS_CELLS = 16384 / 2;                 // logits[:batch_size] -> first 8192 cells get cls loss
constexpr float NOOBJ_SCALE = 0.5f;
constexpr float COORD_SCALE = 5.0f;

// Per-(cell,slot) loss contribution.
// pred slot layout: offset=p0, dur=p1, conf=p2, cls=p3..p5  (slot1: +6)
// target slot layout: conf, cls, offset, dur                (slot1: +4)
__device__ __forceinline__ float slot_loss(float pc, float l0, float l1, float l2,
                                           float po, float pd,
                                           float tc, float tcls, float to, float td,
                                           bool do_cls) {
    float d = tc - pc;
    bool obj = (tc == 1.0f);
    float w = obj ? 1.0f : ((tc == 0.0f) ? NOOBJ_SCALE : 0.0f);
    float r = w * d * d;

    if (obj) {
        float doff = to - po;
        r += COORD_SCALE * doff * doff;
        float dd = sqrtf(td) - sqrtf(pd);
        r += COORD_SCALE * dd * dd;
    }
    if (do_cls) {
        float x0, x1, x2;
        int idx;
        if (obj) { x0 = l0; x1 = l1; x2 = l2; idx = (int)tcls; }
        else     { x0 = 0.f; x1 = 0.f; x2 = 0.f; idx = 0; }
        float m = fmaxf(x0, fmaxf(x1, x2));
        float lse = logf(expf(x0 - m) + expf(x1 - m) + expf(x2 - m)) + m;
        float li = (idx == 0) ? x0 : ((idx == 1) ? x1 : x2);
        r += lse - li;   // cross-entropy = logsumexp - logit[target]
    }
    return r;
}

// 2 adjacent cells per thread, fully unrolled: 10 float4 loads issued as one
// straight-line batch to maximize memory-level parallelism. Grid covers CELLS
// exactly (8192 blocks x 256 threads x 2 cells = 4,194,304).
__global__ __launch_bounds__(256) void ensemble_loss_kernel(
        const float* __restrict__ pred,
        const float* __restrict__ target,
        double* __restrict__ acc_ws) {
    const long long t = (long long)blockIdx.x * blockDim.x + threadIdx.x;  // 0..2M-1
    const float4* __restrict__ p4 = (const float4*)pred + t * 6;   // 2 cells x 3 float4
    const float4* __restrict__ t4 = (const float4*)target + t * 4; // 2 cells x 2 float4

    // Issue all 10 loads up front (independent; compiler front-loads with
    // progressive vmcnt).
    float4 a0 = p4[0], a1 = p4[1], a2 = p4[2];   // cell 2t
    float4 a3 = p4[3], a4 = p4[4], a5 = p4[5];   // cell 2t+1
    float4 b0 = t4[0], b1 = t4[1];               // cell 2t
    float4 b2 = t4[2], b3 = t4[3];               // cell 2t+1

    // cell0 = 2t < 8192  <=>  t < 4096; cell1 = 2t+1 < 8192  <=>  t < 4096 too.
    const bool do_cls = (t < (CLS_CELLS >> 1));

    float acc = 0.0f;
    // cell 2t:   pred = a0.x..a2.w, target = b0 (slot0), b1 (slot1)
    acc += slot_loss(a0.z, a0.w, a1.x, a1.y, a0.x, a0.y,
                     b0.x, b0.y, b0.z, b0.w, do_cls);
    acc += slot_loss(a2.x, a2.y, a2.z, a2.w, a1.z, a1.w,
                     b1.x, b1.y, b1.z, b1.w, do_cls);
    // cell 2t+1: pred = a3.x..a5.w, target = b2 (slot0), b3 (slot1)
    acc += slot_loss(a3.z, a3.w, a4.x, a4.y, a3.x, a3.y,
                     b2.x, b2.y, b2.z, b2.w, do_cls);
    acc += slot_loss(a5.x, a5.y, a5.z, a5.w, a4.z, a4.w,
                     b3.x, b3.y, b3.z, b3.w, do_cls);

    // wave(64) shuffle reduction
    for (int off = 32; off > 0; off >>= 1)
        acc += __shfl_down(acc, off, 64);

    __shared__ float wsum[4];  // 256 threads = 4 waves
    int lane = threadIdx.x & 63;
    int wv = threadIdx.x >> 6;
    if (lane == 0) wsum[wv] = acc;
    __syncthreads();
    if (threadIdx.x == 0) {
        float s = wsum[0] + wsum[1] + wsum[2] + wsum[3];
        atomicAdd(acc_ws, (double)s);  // device-scope f64 atomic, one per block
    }
}

__global__ void finalize_kernel(const double* __restrict__ acc_ws,
                                float* __restrict__ out) {
    out[0] = (float)(acc_ws[0] * (1.0 / (double)B_SZ));
}

extern "C" void kernel_launch(void* const* d_in, const int* in_sizes, int n_in,
                              void* d_out, int out_size, void* d_ws, size_t ws_size,
                              hipStream_t stream) {
    const float* pred   = (const float*)d_in[0];
    const float* target = (const float*)d_in[1];
    float* out = (float*)d_out;
    double* acc = (double*)d_ws;

    // d_ws is poisoned 0xAA before every launch — zero the accumulator.
    hipMemsetAsync(d_ws, 0, sizeof(double), stream);

    // Exact cover: 8192 blocks x 256 threads x 2 cells = 4,194,304 cells.
    ensemble_loss_kernel<<<8192, 256, 0, stream>>>(pred, target, acc);
    finalize_kernel<<<1, 1, 0, stream>>>(acc, out);
}

// Round 3
// 353.594 us; speedup vs baseline: 1.0347x; 1.0347x over previous
//
#include <hip/hip_runtime.h>
#include <math.h>

// Problem constants (from reference)
constexpr int B_SZ = 16384;
constexpr long long CELLS = 4194304;   // 16384*256 cells, 2 anchor slots each
constexpr int CLS_CELLS = 8192;        // logits[:batch_size] -> first 8192 cells get cls loss
constexpr float NOOBJ_SCALE = 0.5f;
constexpr float COORD_SCALE = 5.0f;

constexpr int TPB = 256;               // threads per block == cells per block
constexpr int PRED_PITCH = 13;         // 12 floats + 1 pad (odd stride -> 2-way LDS = free)
constexpr int TGT_PITCH  = 9;          // 8 floats + 1 pad
constexpr int NSLOTS = 64;             // atomic scatter slots in d_ws

// Per-(cell,slot) loss contribution.
// pred slot layout: offset=p0, dur=p1, conf=p2, cls=p3..p5  (slot1: +6)
// target slot layout: conf, cls, offset, dur                (slot1: +4)
__device__ __forceinline__ float slot_loss(float pc, float l0, float l1, float l2,
                                           float po, float pd,
                                           float tc, float tcls, float to, float td,
                                           bool do_cls) {
    float d = tc - pc;
    bool obj = (tc == 1.0f);
    float w = obj ? 1.0f : ((tc == 0.0f) ? NOOBJ_SCALE : 0.0f);
    float r = w * d * d;

    if (obj) {
        float doff = to - po;
        r += COORD_SCALE * doff * doff;
        float dd = sqrtf(td) - sqrtf(pd);
        r += COORD_SCALE * dd * dd;
    }
    if (do_cls) {
        float x0, x1, x2;
        int idx;
        if (obj) { x0 = l0; x1 = l1; x2 = l2; idx = (int)tcls; }
        else     { x0 = 0.f; x1 = 0.f; x2 = 0.f; idx = 0; }
        float m = fmaxf(x0, fmaxf(x1, x2));
        float lse = logf(expf(x0 - m) + expf(x1 - m) + expf(x2 - m)) + m;
        float li = (idx == 0) ? x0 : ((idx == 1) ? x1 : x2);
        r += lse - li;   // cross-entropy = logsumexp - logit[target]
    }
    return r;
}

__global__ __launch_bounds__(256) void ensemble_loss_kernel(
        const float* __restrict__ pred,
        const float* __restrict__ target,
        double* __restrict__ acc_ws) {
    // Padded LDS tiles: 256*13*4 = 13312 B + 256*9*4 = 9216 B = ~22.5 KB
    __shared__ float spred[TPB * PRED_PITCH];
    __shared__ float star[TPB * TGT_PITCH];
    __shared__ float wsum[4];

    const int tid = threadIdx.x;
    const long long cell0 = (long long)blockIdx.x * TPB;

    // ---- stage pred: 768 float4/block, lane-contiguous (coalesced) ----
    // float4 #g covers words 4g..4g+3; 3 float4 per cell, never straddles.
    const float4* __restrict__ pbase = (const float4*)pred + cell0 * 3;
    #pragma unroll
    for (int r = 0; r < 3; ++r) {
        int g = r * TPB + tid;              // 0..767
        float4 v = pbase[g];
        int cell = g / 3;                   // magic-mul div
        int sub  = g - cell * 3;
        int a = cell * PRED_PITCH + 4 * sub;
        spred[a + 0] = v.x; spred[a + 1] = v.y;
        spred[a + 2] = v.z; spred[a + 3] = v.w;
    }
    // ---- stage target: 512 float4/block, lane-contiguous ----
    const float4* __restrict__ tbase = (const float4*)target + cell0 * 2;
    #pragma unroll
    for (int r = 0; r < 2; ++r) {
        int g = r * TPB + tid;              // 0..511
        float4 v = tbase[g];
        int cell = g >> 1;
        int sub  = g & 1;
        int a = cell * TGT_PITCH + 4 * sub;
        star[a + 0] = v.x; star[a + 1] = v.y;
        star[a + 2] = v.z; star[a + 3] = v.w;
    }
    __syncthreads();

    // ---- compute: thread t handles cell (cell0 + t); padded stride reads
    //      are 2 lanes/bank (free) ----
    const float* P = &spred[tid * PRED_PITCH];
    const float* T = &star[tid * TGT_PITCH];
    const bool do_cls = (cell0 + tid) < CLS_CELLS;

    float acc = 0.0f;
    acc += slot_loss(P[2], P[3], P[4], P[5], P[0], P[1],
                     T[0], T[1], T[2], T[3], do_cls);
    acc += slot_loss(P[8], P[9], P[10], P[11], P[6], P[7],
                     T[4], T[5], T[6], T[7], do_cls);

    // wave(64) shuffle reduction
    for (int off = 32; off > 0; off >>= 1)
        acc += __shfl_down(acc, off, 64);

    int lane = tid & 63;
    int wv = tid >> 6;
    if (lane == 0) wsum[wv] = acc;
    __syncthreads();
    if (tid == 0) {
        float s = wsum[0] + wsum[1] + wsum[2] + wsum[3];
        // scatter atomics across 64 slots: ~256 adds/slot, no serialization hotspot
        atomicAdd(&acc_ws[blockIdx.x & (NSLOTS - 1)], (double)s);
    }
}

__global__ void finalize_kernel(const double* __restrict__ acc_ws,
                                float* __restrict__ out) {
    double s = 0.0;
    #pragma unroll
    for (int i = 0; i < NSLOTS; ++i) s += acc_ws[i];
    out[0] = (float)(s * (1.0 / (double)B_SZ));
}

extern "C" void kernel_launch(void* const* d_in, const int* in_sizes, int n_in,
                              void* d_out, int out_size, void* d_ws, size_t ws_size,
                              hipStream_t stream) {
    const float* pred   = (const float*)d_in[0];
    const float* target = (const float*)d_in[1];
    float* out = (float*)d_out;
    double* acc = (double*)d_ws;

    // d_ws is poisoned 0xAA before every launch — zero the 64 accumulator slots.
    hipMemsetAsync(d_ws, 0, NSLOTS * sizeof(double), stream);

    // 16384 blocks x 256 threads, 1 cell/thread, exact cover.
    ensemble_loss_kernel<<<(int)(CELLS / TPB), TPB, 0, stream>>>(pred, target, acc);
    finalize_kernel<<<1, 1, 0, stream>>>(acc, out);
}